// Round 1
// baseline (37328.329 us; speedup 1.0000x reference)
//
#include <hip/hip_runtime.h>
#include <math.h>

// RNN with short-term plasticity: persistent cooperative kernel, 1 grid
// barrier per time step, double-buffered activity broadcast through d_ws.
//
// Sizes (fixed by the reference):
#define NH 1024
#define NB 32
#define NI 8
#define NO 8
#define TSTEPS 1000

#define NWG 256
#define BLK 512

// d_out float offsets (z, h, r, u concatenated flat, each [b][t][...])
#define OFF_Z 0
#define OFF_H (NB * TSTEPS * NO)            // 256000
#define OFF_R (OFF_H + NB * TSTEPS * NH)    // 33024000
#define OFF_U (OFF_R + NB * TSTEPS * NH)    // 65792000

// d_ws float offsets
#define WS_AT 256                  // byte 1024: AT[2][NH][NB]  (A transposed, dbuf)
#define WS_HT (WS_AT + 2 * NH * NB) // HT[2][NB][NH] (tanh(h), parity-buffered)

__device__ __forceinline__ void gridbar(unsigned* bar, unsigned target) {
    __syncthreads();
    if (threadIdx.x == 0) {
        __threadfence();  // belt & suspenders; release below also orders
        __hip_atomic_fetch_add(bar, 1u, __ATOMIC_RELEASE, __HIP_MEMORY_SCOPE_AGENT);
        while (__hip_atomic_load(bar, __ATOMIC_ACQUIRE, __HIP_MEMORY_SCOPE_AGENT) < target) {
            __builtin_amdgcn_s_sleep(2);
        }
        __threadfence();
    }
    __syncthreads();
}

__global__ __launch_bounds__(BLK, 2) void rnn_stp_kernel(
    const float* __restrict__ x,     // [32][1000][8]
    const float* __restrict__ h0,    // [32][1024]
    const float* __restrict__ r0,    // [32][1024]
    const float* __restrict__ u0,    // [32][1024]
    const float* __restrict__ prel,  // [1024]
    const float* __restrict__ scal,  // [1024]
    const float* __restrict__ Wih,   // [1024][8]
    const float* __restrict__ Whh,   // [1024][1024]
    const float* __restrict__ Wmask, // [1024][1024]
    const float* __restrict__ Whz,   // [8][1024]
    float* __restrict__ out,
    float* __restrict__ ws)
{
    const int tid = threadIdx.x;
    const int g   = blockIdx.x;

    unsigned* bar = (unsigned*)ws;
    float* AT = ws + WS_AT;   // [2][NH][NB]
    float* HT = ws + WS_HT;   // [2][NB][NH]

    // Neuron-chunk ownership with XCD swizzle (blockIdx%8 -> XCD heuristic):
    // XCD x owns chunks [32x, 32x+32) -> i in [128x, 128x+128). Consecutive
    // chunks (4 neurons = 16B of an output line) share an XCD so partial
    // 16B output writes merge to full 64B lines in that XCD's L2.
    const int chunk = (g & 7) * 32 + (g >> 3);
    const int ib = chunk * 4;                 // first owned neuron

    __shared__ float red[BLK * 4];            // GEMM K-split partials
    __shared__ float zred[8];                 // z wave partials

    // ---- GEMM role decomposition: tid = ks*32 + il*8 + bg ----
    const int bg = tid & 7;          // batch group: b0 = bg*4
    const int il = (tid >> 3) & 3;   // local neuron 0..3
    const int ks = tid >> 5;         // K split 0..15, j in [ks*64, ks*64+64)
    const int irow = ib + il;

    // Preload masked W row segment into 64 VGPRs (never re-read).
    float w[64];
    {
        const float* wp = Whh   + irow * NH + ks * 64;
        const float* mp = Wmask + irow * NH + ks * 64;
        #pragma unroll
        for (int jj = 0; jj < 64; ++jj) w[jj] = wp[jj] * mp[jj];
    }

    // ---- z role: WG g computes z[b=g>>3][o=g&7]; thread covers 2 neurons ----
    const int bz = g >> 3, oz = g & 7;
    const float wz0 = Whz[oz * NH + 2 * tid];
    const float wz1 = Whz[oz * NH + 2 * tid + 1];

    // ---- owner role: tid<128, b = tid>>2, neuron = ib + (tid&3) ----
    const bool own = tid < 128;
    const int ob = tid >> 2;
    const int oi = ib + (tid & 3);
    float h = 0.f, r = 0.f, u = 0.f, htr = 0.f, p = 0.f, sc = 0.f;
    float wih[8];
    if (own) {
        h  = h0[ob * NH + oi];
        r  = r0[ob * NH + oi];
        u  = u0[ob * NH + oi];
        p  = prel[oi];
        sc = scal[oi];
        #pragma unroll
        for (int k = 0; k < 8; ++k) wih[k] = Wih[oi * NI + k];
        htr = tanhf(h);
        AT[oi * NB + ob] = r * sc * htr;      // A for t=0
    }

    unsigned target = NWG;
    gridbar(bar, target); target += NWG;

    int cur = 0;
    for (int t = 0; t < TSTEPS; ++t) {
        // ---- recurrent GEMM: rec[b][i] = sum_j A[b][j] * Weff[i][j] ----
        const float4* Ab = (const float4*)(AT + cur * NH * NB) + ks * 64 * (NB / 4) + bg;
        float4 acc = make_float4(0.f, 0.f, 0.f, 0.f);
        #pragma unroll
        for (int jj = 0; jj < 64; ++jj) {
            float4 a = Ab[jj * (NB / 4)];
            float wv = w[jj];
            acc.x = fmaf(a.x, wv, acc.x);
            acc.y = fmaf(a.y, wv, acc.y);
            acc.z = fmaf(a.z, wv, acc.z);
            acc.w = fmaf(a.w, wv, acc.w);
        }
        ((float4*)red)[tid] = acc;
        __syncthreads();

        // ---- z for step t-1 (parity (t-1)&1 == (t+1)&1), overlaps owner work ----
        float zp = 0.f;
        if (t > 0) {
            const float* HTp = HT + ((t + 1) & 1) * NB * NH + bz * NH + 2 * tid;
            float2 ht2 = *(const float2*)HTp;
            zp = fmaf(ht2.x, wz0, ht2.y * wz1);
            #pragma unroll
            for (int m = 1; m < 64; m <<= 1) zp += __shfl_xor(zp, m, 64);
            if ((tid & 63) == 0) zred[tid >> 6] = zp;
        }

        // ---- owner: reduce K-split, update state, write outputs ----
        if (own) {
            float rec = 0.f;
            #pragma unroll
            for (int k2 = 0; k2 < 16; ++k2)
                rec += red[(k2 * 32 + (tid & 3) * 8 + (ob >> 2)) * 4 + (ob & 3)];

            const float* xp = x + (ob * TSTEPS + t) * NI;
            float xv = 0.f;
            #pragma unroll
            for (int k = 0; k < 8; ++k) xv = fmaf(xp[k], wih[k], xv);

            float drive = 0.5f * (1.0f + htr);
            float rn = r + ((p - r) / 0.2f - 10.0f * r * drive) * 0.001f;
            float un = u + ((p - u) / 1.5f + 10.0f * (1.0f - u) * drive) * 0.001f;
            float hn = h + ((-h + xv + rec) / 0.01f) * 0.001f;
            float htn = tanhf(hn);

            out[OFF_H + (ob * TSTEPS + t) * NH + oi] = hn;
            out[OFF_R + (ob * TSTEPS + t) * NH + oi] = rn;
            out[OFF_U + (ob * TSTEPS + t) * NH + oi] = un;

            AT[(cur ^ 1) * NH * NB + oi * NB + ob] = rn * sc * htn; // A for t+1
            HT[(t & 1) * NB * NH + ob * NH + oi] = htn;             // for z[t]

            h = hn; r = rn; u = un; htr = htn;
        }

        if (t > 0) {
            __syncthreads();
            if (tid == 0) {
                float z = 0.f;
                #pragma unroll
                for (int wv2 = 0; wv2 < 8; ++wv2) z += zred[wv2];
                out[OFF_Z + (bz * TSTEPS + (t - 1)) * NO + oz] = z;
            }
        }

        gridbar(bar, target); target += NWG;
        cur ^= 1;
    }

    // ---- epilogue: z for t=999 (parity 1) ----
    {
        const float* HTp = HT + ((TSTEPS + 1) & 1) * NB * NH + bz * NH + 2 * tid;
        float2 ht2 = *(const float2*)HTp;
        float zp = fmaf(ht2.x, wz0, ht2.y * wz1);
        #pragma unroll
        for (int m = 1; m < 64; m <<= 1) zp += __shfl_xor(zp, m, 64);
        if ((tid & 63) == 0) zred[tid >> 6] = zp;
        __syncthreads();
        if (tid == 0) {
            float z = 0.f;
            #pragma unroll
            for (int wv2 = 0; wv2 < 8; ++wv2) z += zred[wv2];
            out[OFF_Z + (bz * TSTEPS + 999) * NO + oz] = z;
        }
    }
}

extern "C" void kernel_launch(void* const* d_in, const int* in_sizes, int n_in,
                              void* d_out, int out_size, void* d_ws, size_t ws_size,
                              hipStream_t stream) {
    const float* x     = (const float*)d_in[0];
    const float* h0    = (const float*)d_in[1];
    const float* r0    = (const float*)d_in[2];
    const float* u0    = (const float*)d_in[3];
    const float* prel  = (const float*)d_in[4];
    const float* scal  = (const float*)d_in[5];
    const float* Wih   = (const float*)d_in[6];
    const float* Whh   = (const float*)d_in[7];
    const float* Wmask = (const float*)d_in[8];
    const float* Whz   = (const float*)d_in[9];
    float* out = (float*)d_out;
    float* ws  = (float*)d_ws;

    // Zero the grid-barrier counter (deterministic across graph replays).
    hipMemsetAsync(d_ws, 0, 1024, stream);

    void* args[] = { &x, &h0, &r0, &u0, &prel, &scal,
                     &Wih, &Whh, &Wmask, &Whz, &out, &ws };
    hipLaunchCooperativeKernel((void*)rnn_stp_kernel, dim3(NWG), dim3(BLK),
                               args, 0, stream);
}

// Round 2
// 36422.128 us; speedup vs baseline: 1.0249x; 1.0249x over previous
//
#include <hip/hip_runtime.h>
#include <math.h>

// RNN with short-term plasticity: persistent cooperative kernel, 1 grid
// barrier per time step, double-buffered activity broadcast through d_ws.
//
// Round 2: cheap barrier. Round-1 spent ~95% of time in cache-maintenance
// storms (acquire-load per poll iteration = L2 invalidate per poll).
// Now: exactly ONE __threadfence (wbl2+inv) per WG per step, relaxed
// increments to 8 sharded counters, relaxed polling, odd-stride LDS red.
//
#define NH 1024
#define NB 32
#define NI 8
#define NO 8
#define TSTEPS 1000

#define NWG 256
#define BLK 512

// d_out float offsets (z, h, r, u concatenated flat, each [b][t][...])
#define OFF_Z 0
#define OFF_H (NB * TSTEPS * NO)            // 256000
#define OFF_R (OFF_H + NB * TSTEPS * NH)    // 33024000
#define OFF_U (OFF_R + NB * TSTEPS * NH)    // 65792000

// d_ws float offsets
#define WS_AT 256                   // byte 1024: AT[2][NH][NB]  (A transposed, dbuf)
#define WS_HT (WS_AT + 2 * NH * NB) // HT[2][NB][NH] (tanh(h), parity-buffered)

// Barrier: 8 counters, one 128B line apart, at ws bytes [0,1024).
// WG g increments counter (g&7); each counter gets 32 increments per phase.
__device__ __forceinline__ void cheap_gridbar(unsigned* bar, int g, unsigned tgt) {
    __syncthreads();                 // all waves' stores drained to L2 (vmcnt)
    if (threadIdx.x < 64) {
        __threadfence();             // ONE wbl2+inv per CU per step (wave 0)
    }
    if (threadIdx.x == 0) {
        __hip_atomic_fetch_add(&bar[(g & 7) * 32], 1u,
                               __ATOMIC_RELAXED, __HIP_MEMORY_SCOPE_AGENT);
    }
    if (threadIdx.x < 8) {
        while (__hip_atomic_load(&bar[threadIdx.x * 32],
                                 __ATOMIC_RELAXED, __HIP_MEMORY_SCOPE_AGENT) < tgt) {
            __builtin_amdgcn_s_sleep(2);
        }
    }
    __syncthreads();
}

__global__ __launch_bounds__(BLK, 2) void rnn_stp_kernel(
    const float* __restrict__ x,     // [32][1000][8]
    const float* __restrict__ h0,    // [32][1024]
    const float* __restrict__ r0,    // [32][1024]
    const float* __restrict__ u0,    // [32][1024]
    const float* __restrict__ prel,  // [1024]
    const float* __restrict__ scal,  // [1024]
    const float* __restrict__ Wih,   // [1024][8]
    const float* __restrict__ Whh,   // [1024][1024]
    const float* __restrict__ Wmask, // [1024][1024]
    const float* __restrict__ Whz,   // [8][1024]
    float* __restrict__ out,
    float* __restrict__ ws)
{
    const int tid = threadIdx.x;
    const int g   = blockIdx.x;

    unsigned* bar = (unsigned*)ws;
    float* AT = ws + WS_AT;   // [2][NH][NB]
    float* HT = ws + WS_HT;   // [2][NB][NH]

    // Neuron-chunk ownership with XCD swizzle (blockIdx%8 -> XCD heuristic):
    // 4 consecutive chunks (one 64B output line) land on the same XCD so the
    // partial 16B output writes merge in that XCD's L2.
    const int chunk = (g & 7) * 32 + (g >> 3);
    const int ib = chunk * 4;                 // first owned neuron

    __shared__ float red[128 * 17];           // [own_lin][ks], odd stride: <=2-way banks
    __shared__ float zred[8];                 // z wave partials

    // ---- GEMM role decomposition: tid = ks*32 + il*8 + bg ----
    const int bg = tid & 7;          // batch group: b0 = bg*4
    const int il = (tid >> 3) & 3;   // local neuron 0..3
    const int ks = tid >> 5;         // K split 0..15, j in [ks*64, ks*64+64)
    const int irow = ib + il;

    // Preload masked W row segment into 64 VGPRs (never re-read).
    float w[64];
    {
        const float* wp = Whh   + irow * NH + ks * 64;
        const float* mp = Wmask + irow * NH + ks * 64;
        #pragma unroll
        for (int jj = 0; jj < 64; ++jj) w[jj] = wp[jj] * mp[jj];
    }

    // ---- z role: WG g computes z[b=g>>3][o=g&7]; thread covers 2 neurons ----
    const int bz = g >> 3, oz = g & 7;
    const float wz0 = Whz[oz * NH + 2 * tid];
    const float wz1 = Whz[oz * NH + 2 * tid + 1];

    // ---- owner role: tid<128, b = tid>>2, neuron = ib + (tid&3) ----
    const bool own = tid < 128;
    const int ob = tid >> 2;
    const int oi = ib + (tid & 3);
    float h = 0.f, r = 0.f, u = 0.f, htr = 0.f, p = 0.f, sc = 0.f;
    float wih[8];
    if (own) {
        h  = h0[ob * NH + oi];
        r  = r0[ob * NH + oi];
        u  = u0[ob * NH + oi];
        p  = prel[oi];
        sc = scal[oi];
        #pragma unroll
        for (int k = 0; k < 8; ++k) wih[k] = Wih[oi * NI + k];
        htr = tanhf(h);
        AT[oi * NB + ob] = r * sc * htr;      // A for t=0
    }

    unsigned tgt = 32;
    cheap_gridbar(bar, g, tgt); tgt += 32;

    int cur = 0;
    for (int t = 0; t < TSTEPS; ++t) {
        // ---- recurrent GEMM: rec[b][i] = sum_j A[b][j] * Weff[i][j] ----
        const float4* Ab = (const float4*)(AT + cur * NH * NB) + ks * 64 * (NB / 4) + bg;
        float4 acc = make_float4(0.f, 0.f, 0.f, 0.f);
        #pragma unroll
        for (int jj = 0; jj < 64; ++jj) {
            float4 a = Ab[jj * (NB / 4)];
            float wv = w[jj];
            acc.x = fmaf(a.x, wv, acc.x);
            acc.y = fmaf(a.y, wv, acc.y);
            acc.z = fmaf(a.z, wv, acc.z);
            acc.w = fmaf(a.w, wv, acc.w);
        }
        // red[own_lin][ks], own_lin = b*4 + il = (bg*4+q)*4 + il
        {
            const int base = (bg * 16 + il) * 17 + ks;
            red[base          ] = acc.x;   // q=0
            red[base + 4  * 17] = acc.y;   // q=1
            red[base + 8  * 17] = acc.z;   // q=2
            red[base + 12 * 17] = acc.w;   // q=3
        }
        __syncthreads();

        // ---- z for step t-1 (parity (t-1)&1 == (t+1)&1), overlaps owner work ----
        float zp = 0.f;
        if (t > 0) {
            const float* HTp = HT + ((t + 1) & 1) * NB * NH + bz * NH + 2 * tid;
            float2 ht2 = *(const float2*)HTp;
            zp = fmaf(ht2.x, wz0, ht2.y * wz1);
            #pragma unroll
            for (int m = 1; m < 64; m <<= 1) zp += __shfl_xor(zp, m, 64);
            if ((tid & 63) == 0) zred[tid >> 6] = zp;
        }

        // ---- owner: reduce K-split, update state, write outputs ----
        if (own) {
            float rec = 0.f;
            #pragma unroll
            for (int k2 = 0; k2 < 16; ++k2)
                rec += red[tid * 17 + k2];

            const float* xp = x + (ob * TSTEPS + t) * NI;
            float xv = 0.f;
            #pragma unroll
            for (int k = 0; k < 8; ++k) xv = fmaf(xp[k], wih[k], xv);

            float drive = 0.5f * (1.0f + htr);
            float rn = r + ((p - r) / 0.2f - 10.0f * r * drive) * 0.001f;
            float un = u + ((p - u) / 1.5f + 10.0f * (1.0f - u) * drive) * 0.001f;
            float hn = h + ((-h + xv + rec) / 0.01f) * 0.001f;
            float htn = tanhf(hn);

            out[OFF_H + (ob * TSTEPS + t) * NH + oi] = hn;
            out[OFF_R + (ob * TSTEPS + t) * NH + oi] = rn;
            out[OFF_U + (ob * TSTEPS + t) * NH + oi] = un;

            AT[(cur ^ 1) * NH * NB + oi * NB + ob] = rn * sc * htn; // A for t+1
            HT[(t & 1) * NB * NH + ob * NH + oi] = htn;             // for z[t]

            h = hn; r = rn; u = un; htr = htn;
        }

        if (t > 0) {
            __syncthreads();
            if (tid == 0) {
                float z = 0.f;
                #pragma unroll
                for (int wv2 = 0; wv2 < 8; ++wv2) z += zred[wv2];
                out[OFF_Z + (bz * TSTEPS + (t - 1)) * NO + oz] = z;
            }
        }

        cheap_gridbar(bar, g, tgt); tgt += 32;
        cur ^= 1;
    }

    // ---- epilogue: z for t=999 (parity 1) ----
    {
        const float* HTp = HT + ((TSTEPS + 1) & 1) * NB * NH + bz * NH + 2 * tid;
        float2 ht2 = *(const float2*)HTp;
        float zp = fmaf(ht2.x, wz0, ht2.y * wz1);
        #pragma unroll
        for (int m = 1; m < 64; m <<= 1) zp += __shfl_xor(zp, m, 64);
        if ((tid & 63) == 0) zred[tid >> 6] = zp;
        __syncthreads();
        if (tid == 0) {
            float z = 0.f;
            #pragma unroll
            for (int wv2 = 0; wv2 < 8; ++wv2) z += zred[wv2];
            out[OFF_Z + (bz * TSTEPS + 999) * NO + oz] = z;
        }
    }
}

extern "C" void kernel_launch(void* const* d_in, const int* in_sizes, int n_in,
                              void* d_out, int out_size, void* d_ws, size_t ws_size,
                              hipStream_t stream) {
    const float* x     = (const float*)d_in[0];
    const float* h0    = (const float*)d_in[1];
    const float* r0    = (const float*)d_in[2];
    const float* u0    = (const float*)d_in[3];
    const float* prel  = (const float*)d_in[4];
    const float* scal  = (const float*)d_in[5];
    const float* Wih   = (const float*)d_in[6];
    const float* Whh   = (const float*)d_in[7];
    const float* Wmask = (const float*)d_in[8];
    const float* Whz   = (const float*)d_in[9];
    float* out = (float*)d_out;
    float* ws  = (float*)d_ws;

    // Zero the barrier counters (deterministic across graph replays).
    hipMemsetAsync(d_ws, 0, 1024, stream);

    void* args[] = { &x, &h0, &r0, &u0, &prel, &scal,
                     &Wih, &Whh, &Wmask, &Whz, &out, &ws };
    hipLaunchCooperativeKernel((void*)rnn_stp_kernel, dim3(NWG), dim3(BLK),
                               args, 0, stream);
}

// Round 3
// 23658.759 us; speedup vs baseline: 1.5778x; 1.5395x over previous
//
#include <hip/hip_runtime.h>
#include <math.h>

// RNN with short-term plasticity: persistent cooperative kernel, 1 grid
// barrier per time step, double-buffered activity broadcast through d_ws.
//
// Round 3: NO buffer_wbl2. Cross-WG data (AT/HT) is written through to the
// coherence point with agent-scope relaxed atomic stores (sc0 sc1); the
// barrier release is just syncthreads (vmcnt ack) + relaxed counter add.
// Acquire is an invalidate-only agent fence (buffer_inv sc1) in wave 0.
// Round-2's per-step __threadfence (wbl2 = full L2 writeback walk per CU
// per step) was the hypothesized 30+ us/step cost.
//
#define NH 1024
#define NB 32
#define NI 8
#define NO 8
#define TSTEPS 1000

#define NWG 256
#define BLK 512

// d_out float offsets (z, h, r, u concatenated flat, each [b][t][...])
#define OFF_Z 0
#define OFF_H (NB * TSTEPS * NO)            // 256000
#define OFF_R (OFF_H + NB * TSTEPS * NH)    // 33024000
#define OFF_U (OFF_R + NB * TSTEPS * NH)    // 65792000

// d_ws float offsets
#define WS_AT 256                   // byte 1024: AT[2][NH][NB]  (A transposed, dbuf)
#define WS_HT (WS_AT + 2 * NH * NB) // HT[2][NB][NH] (tanh(h), parity-buffered)

// Barrier: 8 counters, one 128B line apart, at ws bytes [0,1024).
// WG g increments counter (g&7); each counter gets 32 increments per phase.
// Release ordering: callers' write-through stores are vmcnt-ack'd by the
// __syncthreads below before thread 0 increments. Acquire: inv-only fence.
__device__ __forceinline__ void cheap_gridbar(unsigned* bar, int g, unsigned tgt) {
    __syncthreads();                 // all waves' stores ack'd at coherence pt
    if (threadIdx.x == 0) {
        __hip_atomic_fetch_add(&bar[(g & 7) * 32], 1u,
                               __ATOMIC_RELAXED, __HIP_MEMORY_SCOPE_AGENT);
    }
    if (threadIdx.x < 8) {
        while (__hip_atomic_load(&bar[threadIdx.x * 32],
                                 __ATOMIC_RELAXED, __HIP_MEMORY_SCOPE_AGENT) < tgt) {
            __builtin_amdgcn_s_sleep(2);
        }
    }
    if (threadIdx.x < 64) {
        // invalidate-only: drop stale L1/L2 copies of AT/HT; no writeback walk
        __builtin_amdgcn_fence(__ATOMIC_ACQUIRE, "agent");
    }
    __syncthreads();
}

__global__ __launch_bounds__(BLK, 2) void rnn_stp_kernel(
    const float* __restrict__ x,     // [32][1000][8]
    const float* __restrict__ h0,    // [32][1024]
    const float* __restrict__ r0,    // [32][1024]
    const float* __restrict__ u0,    // [32][1024]
    const float* __restrict__ prel,  // [1024]
    const float* __restrict__ scal,  // [1024]
    const float* __restrict__ Wih,   // [1024][8]
    const float* __restrict__ Whh,   // [1024][1024]
    const float* __restrict__ Wmask, // [1024][1024]
    const float* __restrict__ Whz,   // [8][1024]
    float* __restrict__ out,
    float* __restrict__ ws)
{
    const int tid = threadIdx.x;
    const int g   = blockIdx.x;

    unsigned* bar = (unsigned*)ws;
    float* AT = ws + WS_AT;   // [2][NH][NB]
    float* HT = ws + WS_HT;   // [2][NB][NH]

    // Neuron-chunk ownership with XCD swizzle (blockIdx%8 -> XCD heuristic):
    // 4 consecutive chunks (one 64B output line) land on the same XCD so the
    // partial 16B output writes merge in that XCD's L2.
    const int chunk = (g & 7) * 32 + (g >> 3);
    const int ib = chunk * 4;                 // first owned neuron

    __shared__ float red[128 * 17];           // [own_lin][ks], odd stride
    __shared__ float zred[8];                 // z wave partials

    // ---- GEMM role decomposition: tid = ks*32 + il*8 + bg ----
    const int bg = tid & 7;          // batch group: b0 = bg*4
    const int il = (tid >> 3) & 3;   // local neuron 0..3
    const int ks = tid >> 5;         // K split 0..15, j in [ks*64, ks*64+64)
    const int irow = ib + il;

    // Preload masked W row segment into 64 VGPRs (never re-read).
    float w[64];
    {
        const float* wp = Whh   + irow * NH + ks * 64;
        const float* mp = Wmask + irow * NH + ks * 64;
        #pragma unroll
        for (int jj = 0; jj < 64; ++jj) w[jj] = wp[jj] * mp[jj];
    }

    // ---- z role: WG g computes z[b=g>>3][o=g&7]; thread covers 2 neurons ----
    const int bz = g >> 3, oz = g & 7;
    const float wz0 = Whz[oz * NH + 2 * tid];
    const float wz1 = Whz[oz * NH + 2 * tid + 1];

    // ---- owner role: tid<128, b = tid>>2, neuron = ib + (tid&3) ----
    const bool own = tid < 128;
    const int ob = tid >> 2;
    const int oi = ib + (tid & 3);
    float h = 0.f, r = 0.f, u = 0.f, htr = 0.f, p = 0.f, sc = 0.f;
    float wih[8];
    if (own) {
        h  = h0[ob * NH + oi];
        r  = r0[ob * NH + oi];
        u  = u0[ob * NH + oi];
        p  = prel[oi];
        sc = scal[oi];
        #pragma unroll
        for (int k = 0; k < 8; ++k) wih[k] = Wih[oi * NI + k];
        htr = tanhf(h);
        __hip_atomic_store(&AT[oi * NB + ob], r * sc * htr,
                           __ATOMIC_RELAXED, __HIP_MEMORY_SCOPE_AGENT);
    }

    unsigned tgt = 32;
    cheap_gridbar(bar, g, tgt); tgt += 32;

    int cur = 0;
    for (int t = 0; t < TSTEPS; ++t) {
        // ---- prefetch x early; consumed after GEMM (hides HBM latency) ----
        float4 xa = make_float4(0.f, 0.f, 0.f, 0.f), xb = xa;
        if (own) {
            const float4* xp = (const float4*)(x + (ob * TSTEPS + t) * NI);
            xa = xp[0];
            xb = xp[1];
        }

        // ---- recurrent GEMM: rec[b][i] = sum_j A[b][j] * Weff[i][j] ----
        const float4* Ab = (const float4*)(AT + cur * NH * NB) + ks * 64 * (NB / 4) + bg;
        float4 acc = make_float4(0.f, 0.f, 0.f, 0.f);
        #pragma unroll
        for (int jj = 0; jj < 64; ++jj) {
            float4 a = Ab[jj * (NB / 4)];
            float wv = w[jj];
            acc.x = fmaf(a.x, wv, acc.x);
            acc.y = fmaf(a.y, wv, acc.y);
            acc.z = fmaf(a.z, wv, acc.z);
            acc.w = fmaf(a.w, wv, acc.w);
        }
        // red[own_lin][ks], own_lin = b*4 + il = (bg*4+q)*4 + il
        {
            const int base = (bg * 16 + il) * 17 + ks;
            red[base          ] = acc.x;   // q=0
            red[base + 4  * 17] = acc.y;   // q=1
            red[base + 8  * 17] = acc.z;   // q=2
            red[base + 12 * 17] = acc.w;   // q=3
        }
        __syncthreads();

        // ---- z for step t-1 (parity (t-1)&1 == (t+1)&1) ----
        float zp = 0.f;
        if (t > 0) {
            const float* HTp = HT + ((t + 1) & 1) * NB * NH + bz * NH + 2 * tid;
            float2 ht2 = *(const float2*)HTp;
            zp = fmaf(ht2.x, wz0, ht2.y * wz1);
            #pragma unroll
            for (int m = 1; m < 64; m <<= 1) zp += __shfl_xor(zp, m, 64);
            if ((tid & 63) == 0) zred[tid >> 6] = zp;
        }

        // ---- owner: reduce K-split, update state, write outputs ----
        if (own) {
            float rec = 0.f;
            #pragma unroll
            for (int k2 = 0; k2 < 16; ++k2)
                rec += red[tid * 17 + k2];

            float xv = fmaf(xa.x, wih[0], fmaf(xa.y, wih[1],
                       fmaf(xa.z, wih[2], xa.w * wih[3])));
            xv = fmaf(xb.x, wih[4], fmaf(xb.y, wih[5],
                 fmaf(xb.z, wih[6], fmaf(xb.w, wih[7], xv))));

            float drive = 0.5f * (1.0f + htr);
            float rn = r + ((p - r) / 0.2f - 10.0f * r * drive) * 0.001f;
            float un = u + ((p - u) / 1.5f + 10.0f * (1.0f - u) * drive) * 0.001f;
            float hn = h + ((-h + xv + rec) / 0.01f) * 0.001f;
            float htn = tanhf(hn);

            out[OFF_H + (ob * TSTEPS + t) * NH + oi] = hn;
            out[OFF_R + (ob * TSTEPS + t) * NH + oi] = rn;
            out[OFF_U + (ob * TSTEPS + t) * NH + oi] = un;

            // write-through to coherence point (no L2 dirtying, no wbl2 needed)
            __hip_atomic_store(&AT[(cur ^ 1) * NH * NB + oi * NB + ob],
                               rn * sc * htn,
                               __ATOMIC_RELAXED, __HIP_MEMORY_SCOPE_AGENT);
            __hip_atomic_store(&HT[(t & 1) * NB * NH + ob * NH + oi], htn,
                               __ATOMIC_RELAXED, __HIP_MEMORY_SCOPE_AGENT);

            h = hn; r = rn; u = un; htr = htn;
        }

        if (t > 0) {
            __syncthreads();
            if (tid == 0) {
                float z = 0.f;
                #pragma unroll
                for (int wv2 = 0; wv2 < 8; ++wv2) z += zred[wv2];
                out[OFF_Z + (bz * TSTEPS + (t - 1)) * NO + oz] = z;
            }
        }

        cheap_gridbar(bar, g, tgt); tgt += 32;
        cur ^= 1;
    }

    // ---- epilogue: z for t=999 (parity 1) ----
    {
        const float* HTp = HT + ((TSTEPS + 1) & 1) * NB * NH + bz * NH + 2 * tid;
        float2 ht2 = *(const float2*)HTp;
        float zp = fmaf(ht2.x, wz0, ht2.y * wz1);
        #pragma unroll
        for (int m = 1; m < 64; m <<= 1) zp += __shfl_xor(zp, m, 64);
        if ((tid & 63) == 0) zred[tid >> 6] = zp;
        __syncthreads();
        if (tid == 0) {
            float z = 0.f;
            #pragma unroll
            for (int wv2 = 0; wv2 < 8; ++wv2) z += zred[wv2];
            out[OFF_Z + (bz * TSTEPS + 999) * NO + oz] = z;
        }
    }
}

extern "C" void kernel_launch(void* const* d_in, const int* in_sizes, int n_in,
                              void* d_out, int out_size, void* d_ws, size_t ws_size,
                              hipStream_t stream) {
    const float* x     = (const float*)d_in[0];
    const float* h0    = (const float*)d_in[1];
    const float* r0    = (const float*)d_in[2];
    const float* u0    = (const float*)d_in[3];
    const float* prel  = (const float*)d_in[4];
    const float* scal  = (const float*)d_in[5];
    const float* Wih   = (const float*)d_in[6];
    const float* Whh   = (const float*)d_in[7];
    const float* Wmask = (const float*)d_in[8];
    const float* Whz   = (const float*)d_in[9];
    float* out = (float*)d_out;
    float* ws  = (float*)d_ws;

    // Zero the barrier counters (deterministic across graph replays).
    hipMemsetAsync(d_ws, 0, 1024, stream);

    void* args[] = { &x, &h0, &r0, &u0, &prel, &scal,
                     &Wih, &Whh, &Wmask, &Whz, &out, &ws };
    hipLaunchCooperativeKernel((void*)rnn_stp_kernel, dim3(NWG), dim3(BLK),
                               args, 0, stream);
}

// Round 4
// 6445.993 us; speedup vs baseline: 5.7909x; 3.6703x over previous
//
#include <hip/hip_runtime.h>
#include <math.h>

// RNN with short-term plasticity: persistent cooperative kernel, 1 grid
// barrier per time step.
//
// Round 4: ZERO cache-maintenance in the hot loop. All cross-WG data (AT,
// HT, barrier slots) moves via agent-scope relaxed atomics (sc0 sc1 =
// bypass L1+L2, served at the coherence point / L3). No __threadfence, no
// acquire fence, no buffer_inv, no wbl2 — rounds 1-3 showed per-CU
// cache-maintenance walks cost 20-30 us/step. Private data (x, W, out
// h/r/u stream) stays normally cached; out partial lines now merge in L2.
//
// GEMM remap: thread (ks=tid>>3, bg=tid&7) loads its UNIQUE A slice
// (16 j x 4 b, 128 KB/WG/step total, no redundancy) and computes all 4
// owned neurons; in-wave shfl_xor butterfly reduces the 8-way ks split
// inside each wave, tiny LDS pass for the 8-wave combine.
//
#define NH 1024
#define NB 32
#define NI 8
#define NO 8
#define TSTEPS 1000

#define NWG 256
#define BLK 512

// d_out float offsets (z, h, r, u concatenated flat)
#define OFF_Z 0
#define OFF_H (NB * TSTEPS * NO)            // 256000
#define OFF_R (OFF_H + NB * TSTEPS * NH)    // 33024000
#define OFF_U (OFF_R + NB * TSTEPS * NH)    // 65792000

// d_ws float offsets: slots[256] (128B apart), AT[2][NH][NB], HT[2][NB][NH]
#define WS_AT (256 * 32)                    // 8192
#define WS_HT (WS_AT + 2 * NH * NB)         // 8192 + 65536

typedef unsigned long long u64;

// Barrier: WG g stamps its own slot with the step number (plain coherent
// store -> no RMW contention); 256 poller threads each watch one slot.
// Release ordering: __syncthreads drains vmcnt (all agent stores ack'd at
// the coherence point) in every wave before any wave passes s_barrier.
__device__ __forceinline__ void gridbar(unsigned* slot, int g, unsigned stamp) {
    __syncthreads();
    if (threadIdx.x == 0)
        __hip_atomic_store(&slot[g * 32], stamp,
                           __ATOMIC_RELAXED, __HIP_MEMORY_SCOPE_AGENT);
    if (threadIdx.x < NWG) {
        while (__hip_atomic_load(&slot[threadIdx.x * 32],
                                 __ATOMIC_RELAXED, __HIP_MEMORY_SCOPE_AGENT) < stamp)
            __builtin_amdgcn_s_sleep(1);
    }
    __syncthreads();
}

__global__ __launch_bounds__(BLK, 2) void rnn_stp_kernel(
    const float* __restrict__ x,     // [32][1000][8]
    const float* __restrict__ h0,    // [32][1024]
    const float* __restrict__ r0,    // [32][1024]
    const float* __restrict__ u0,    // [32][1024]
    const float* __restrict__ prel,  // [1024]
    const float* __restrict__ scal,  // [1024]
    const float* __restrict__ Wih,   // [1024][8]
    const float* __restrict__ Whh,   // [1024][1024]
    const float* __restrict__ Wmask, // [1024][1024]
    const float* __restrict__ Whz,   // [8][1024]
    float* __restrict__ out,
    float* __restrict__ ws)
{
    const int tid = threadIdx.x;
    const int g   = blockIdx.x;

    unsigned* slot = (unsigned*)ws;
    float* AT = ws + WS_AT;   // [2][NH][NB]
    float* HT = ws + WS_HT;   // [2][NB][NH]

    // XCD swizzle: XCD x (= g&7) owns neurons [128x, 128x+128) so 64B output
    // lines (16 neurons) are fully assembled within one XCD's L2.
    const int chunk = (g & 7) * 32 + (g >> 3);
    const int ib = chunk * 4;                 // first owned neuron

    __shared__ float4 red4[8 * 36];           // [wid][il*9+bg], padded
    __shared__ float zred[8];

    // ---- GEMM roles: ks = tid>>3 (j range [ks*16,+16)), bg = tid&7 (4 b) ----
    const int ks = tid >> 3;
    const int bg = tid & 7;

    // Weights for all 4 owned rows x this thread's 16-j slice (64 VGPRs).
    float w[4][16];
    #pragma unroll
    for (int il = 0; il < 4; ++il) {
        const float* wp = Whh   + (ib + il) * NH + ks * 16;
        const float* mp = Wmask + (ib + il) * NH + ks * 16;
        #pragma unroll
        for (int jj = 0; jj < 16; ++jj) w[il][jj] = wp[jj] * mp[jj];
    }

    // ---- z role: WG g computes z[b=g>>3][o=g&7] ----
    const int bz = g >> 3, oz = g & 7;
    const float wz0 = Whz[oz * NH + 2 * tid];
    const float wz1 = Whz[oz * NH + 2 * tid + 1];

    // ---- owner role: tid<128, b = tid>>2, neuron = ib + (tid&3) ----
    const bool own = tid < 128;
    const int ob   = tid >> 2;
    const int il_o = tid & 3;
    const int oi   = ib + il_o;
    float h = 0.f, r = 0.f, u = 0.f, htr = 0.f, p = 0.f, sc = 0.f;
    float wih[8];
    if (own) {
        h  = h0[ob * NH + oi];
        r  = r0[ob * NH + oi];
        u  = u0[ob * NH + oi];
        p  = prel[oi];
        sc = scal[oi];
        #pragma unroll
        for (int k = 0; k < 8; ++k) wih[k] = Wih[oi * NI + k];
        htr = tanhf(h);
        __hip_atomic_store(&AT[oi * NB + ob], r * sc * htr,
                           __ATOMIC_RELAXED, __HIP_MEMORY_SCOPE_AGENT);
    }

    unsigned stamp = 1;
    gridbar(slot, g, stamp); ++stamp;

    const int lane = tid & 63, wid = tid >> 6;

    for (int t = 0; t < TSTEPS; ++t) {
        const int cur = t & 1;

        // ---- coherent A loads: unique 16 j x 4 b slice (32 x 8B loads) ----
        const float* Ab = AT + cur * NH * NB + ks * 16 * NB + bg * 4;
        float2 a[16][2];
        #pragma unroll
        for (int jj = 0; jj < 16; ++jj) {
            u64 lo = __hip_atomic_load((const u64*)(Ab + jj * NB),
                                       __ATOMIC_RELAXED, __HIP_MEMORY_SCOPE_AGENT);
            u64 hi = __hip_atomic_load((const u64*)(Ab + jj * NB + 2),
                                       __ATOMIC_RELAXED, __HIP_MEMORY_SCOPE_AGENT);
            a[jj][0] = __builtin_bit_cast(float2, lo);
            a[jj][1] = __builtin_bit_cast(float2, hi);
        }

        // ---- x prefetch (cached; read-only data) ----
        float4 xa = make_float4(0.f, 0.f, 0.f, 0.f), xb = xa;
        if (own) {
            const float4* xp = (const float4*)(x + (ob * TSTEPS + t) * NI);
            xa = xp[0];
            xb = xp[1];
        }

        // ---- FMAs: 16 j x 4 il x 4 b ----
        float acc[4][4] = {{0.f,0.f,0.f,0.f},{0.f,0.f,0.f,0.f},
                           {0.f,0.f,0.f,0.f},{0.f,0.f,0.f,0.f}};
        #pragma unroll
        for (int jj = 0; jj < 16; ++jj) {
            #pragma unroll
            for (int il = 0; il < 4; ++il) {
                const float wv = w[il][jj];
                acc[il][0] = fmaf(a[jj][0].x, wv, acc[il][0]);
                acc[il][1] = fmaf(a[jj][0].y, wv, acc[il][1]);
                acc[il][2] = fmaf(a[jj][1].x, wv, acc[il][2]);
                acc[il][3] = fmaf(a[jj][1].y, wv, acc[il][3]);
            }
        }

        // ---- in-wave butterfly over ks bits (lane bits 3..5) ----
        #pragma unroll
        for (int m = 8; m <= 32; m <<= 1) {
            #pragma unroll
            for (int il = 0; il < 4; ++il) {
                #pragma unroll
                for (int q = 0; q < 4; ++q)
                    acc[il][q] += __shfl_xor(acc[il][q], m, 64);
            }
        }
        if (lane < 8) {   // lane == bg; holds wave-sum over its 8 ks groups
            #pragma unroll
            for (int il = 0; il < 4; ++il)
                red4[wid * 36 + il * 9 + lane] =
                    make_float4(acc[il][0], acc[il][1], acc[il][2], acc[il][3]);
        }
        __syncthreads();

        // ---- z partial for step t-1 (coherent HT read, parity (t-1)&1) ----
        if (t > 0) {
            u64 hv = __hip_atomic_load(
                (const u64*)(HT + ((t + 1) & 1) * NB * NH + bz * NH + 2 * tid),
                __ATOMIC_RELAXED, __HIP_MEMORY_SCOPE_AGENT);
            float2 ht2 = __builtin_bit_cast(float2, hv);
            float zp = fmaf(ht2.x, wz0, ht2.y * wz1);
            #pragma unroll
            for (int m = 1; m < 64; m <<= 1) zp += __shfl_xor(zp, m, 64);
            if (lane == 0) zred[wid] = zp;
        }

        // ---- owner: combine 8 wave partials, update state, write out ----
        if (own) {
            float rec = 0.f;
            const float* redf = (const float*)red4;
            #pragma unroll
            for (int wv = 0; wv < 8; ++wv)
                rec += redf[(wv * 36 + il_o * 9 + (ob >> 2)) * 4 + (ob & 3)];

            float xv = fmaf(xa.x, wih[0], fmaf(xa.y, wih[1],
                       fmaf(xa.z, wih[2], xa.w * wih[3])));
            xv = fmaf(xb.x, wih[4], fmaf(xb.y, wih[5],
                 fmaf(xb.z, wih[6], fmaf(xb.w, wih[7], xv))));

            float drive = 0.5f * (1.0f + htr);
            float rn = r + ((p - r) / 0.2f - 10.0f * r * drive) * 0.001f;
            float un = u + ((p - u) / 1.5f + 10.0f * (1.0f - u) * drive) * 0.001f;
            float hn = h + ((-h + xv + rec) / 0.01f) * 0.001f;
            float htn = tanhf(hn);

            out[OFF_H + (ob * TSTEPS + t) * NH + oi] = hn;
            out[OFF_R + (ob * TSTEPS + t) * NH + oi] = rn;
            out[OFF_U + (ob * TSTEPS + t) * NH + oi] = un;

            __hip_atomic_store(&AT[((t + 1) & 1) * NH * NB + oi * NB + ob],
                               rn * sc * htn,
                               __ATOMIC_RELAXED, __HIP_MEMORY_SCOPE_AGENT);
            __hip_atomic_store(&HT[(t & 1) * NB * NH + ob * NH + oi], htn,
                               __ATOMIC_RELAXED, __HIP_MEMORY_SCOPE_AGENT);

            h = hn; r = rn; u = un; htr = htn;
        }

        if (t > 0) {
            __syncthreads();
            if (tid == 0) {
                float z = 0.f;
                #pragma unroll
                for (int wv = 0; wv < 8; ++wv) z += zred[wv];
                out[OFF_Z + (bz * TSTEPS + (t - 1)) * NO + oz] = z;
            }
        }

        gridbar(slot, g, stamp); ++stamp;
    }

    // ---- epilogue: z for t=999 (parity 1) ----
    {
        u64 hv = __hip_atomic_load(
            (const u64*)(HT + ((TSTEPS + 1) & 1) * NB * NH + bz * NH + 2 * tid),
            __ATOMIC_RELAXED, __HIP_MEMORY_SCOPE_AGENT);
        float2 ht2 = __builtin_bit_cast(float2, hv);
        float zp = fmaf(ht2.x, wz0, ht2.y * wz1);
        #pragma unroll
        for (int m = 1; m < 64; m <<= 1) zp += __shfl_xor(zp, m, 64);
        if (lane == 0) zred[wid] = zp;
        __syncthreads();
        if (tid == 0) {
            float z = 0.f;
            #pragma unroll
            for (int wv = 0; wv < 8; ++wv) z += zred[wv];
            out[OFF_Z + (bz * TSTEPS + 999) * NO + oz] = z;
        }
    }
}

extern "C" void kernel_launch(void* const* d_in, const int* in_sizes, int n_in,
                              void* d_out, int out_size, void* d_ws, size_t ws_size,
                              hipStream_t stream) {
    const float* x     = (const float*)d_in[0];
    const float* h0    = (const float*)d_in[1];
    const float* r0    = (const float*)d_in[2];
    const float* u0    = (const float*)d_in[3];
    const float* prel  = (const float*)d_in[4];
    const float* scal  = (const float*)d_in[5];
    const float* Wih   = (const float*)d_in[6];
    const float* Whh   = (const float*)d_in[7];
    const float* Wmask = (const float*)d_in[8];
    const float* Whz   = (const float*)d_in[9];
    float* out = (float*)d_out;
    float* ws  = (float*)d_ws;

    // Zero the 256 barrier slots (128B apart) each launch.
    hipMemsetAsync(d_ws, 0, NWG * 128, stream);

    void* args[] = { &x, &h0, &r0, &u0, &prel, &scal,
                     &Wih, &Whh, &Wmask, &Whz, &out, &ws };
    hipLaunchCooperativeKernel((void*)rnn_stp_kernel, dim3(NWG), dim3(BLK),
                               args, 0, stream);
}